// Round 10
// baseline (321.342 us; speedup 1.0000x reference)
//
#include <hip/hip_runtime.h>
#include <hip/hip_bf16.h>
#include <math.h>

#define B_ 4
#define T_ 2048
#define DM 768
#define H_ 12
#define DH 64

typedef __attribute__((ext_vector_type(4))) float f32x4;
typedef __attribute__((ext_vector_type(8))) short s16x8;

typedef const __attribute__((address_space(1))) void* gas1_t;
typedef __attribute__((address_space(3))) void* las3_t;

__device__ __forceinline__ ushort f2b(float f) {
  union { float f; unsigned u; } v; v.f = f;
  unsigned u = v.u;
  u += 0x7fffu + ((u >> 16) & 1u);
  return (ushort)(u >> 16);
}
__device__ __forceinline__ float b2f(ushort b) {
  union { unsigned u; float f; } v; v.u = ((unsigned)b) << 16;
  return v.f;
}
__device__ __forceinline__ unsigned fbits(float f) {
  union { float f; unsigned u; } v; v.f = f; return v.u;
}

// ---------------- fused prep: x->bf16, 4 weights->bf16, cos/sin pack ----------
__global__ __launch_bounds__(256) void prep(
    const float* __restrict__ x, const float* __restrict__ wq,
    const float* __restrict__ wk, const float* __restrict__ wv,
    const float* __restrict__ wo, const float* __restrict__ rc,
    const float* __restrict__ rs,
    ushort* __restrict__ xb, ushort* __restrict__ wqkv,
    ushort* __restrict__ wob, float2* __restrict__ cs2) {
  int i = blockIdx.x * 256 + threadIdx.x;
  if (i < 1572864) {
    float4 v = ((const float4*)x)[i];
    ushort4 o;
    o.x = f2b(v.x); o.y = f2b(v.y); o.z = f2b(v.z); o.w = f2b(v.w);
    ((ushort4*)xb)[i] = o;
  } else if (i < 2162688) {
    int i2 = i - 1572864;
    int which = i2 / 147456, j = i2 - which * 147456;
    const float* src = which == 0 ? wq : which == 1 ? wk : which == 2 ? wv : wo;
    ushort* dst = which < 3 ? wqkv + (size_t)which * 589824 : wob;
    float4 v = ((const float4*)src)[j];
    ushort4 o;
    o.x = f2b(v.x); o.y = f2b(v.y); o.z = f2b(v.z); o.w = f2b(v.w);
    ((ushort4*)dst)[j] = o;
  } else if (i < 2179072) {
    int j = i - 2162688;
    float4 c = ((const float4*)rc)[j];
    float4 s = ((const float4*)rs)[j];
    float4 o0, o1;
    o0.x = c.x; o0.y = s.x; o0.z = c.y; o0.w = s.y;
    o1.x = c.z; o1.y = s.z; o1.z = c.w; o1.w = s.w;
    ((float4*)cs2)[j * 2] = o0;
    ((float4*)cs2)[j * 2 + 1] = o1;
  }
}

// ---------------- QKV GEMM (R8 form: BK=32, zero-conflict swizzle) -----------
__global__ __launch_bounds__(256) void gemm_qkv(
    const ushort* __restrict__ A, const ushort* __restrict__ Bw,
    const float2* __restrict__ cs2,
    ushort* __restrict__ Qb, ushort* __restrict__ Kb, ushort* __restrict__ Vt) {
  const int K = 768;
  __shared__ ushort As[128 * 32];
  __shared__ ushort Bs[128 * 32];
  const int m0 = blockIdx.y * 128, n0 = blockIdx.x * 128;
  const int tid = threadIdx.x;
  const int wave = tid >> 6, lane = tid & 63;
  const int wm = (wave >> 1) * 64, wn = (wave & 1) * 64;
  const int quad = lane >> 4, l16 = lane & 15;
  const int tr = tid >> 2;
  const int scb = (tid & 3) ^ ((tr >> 1) & 3);
  const int fsw = (l16 >> 1) & 3;

  f32x4 acc[4][4] = {};

  const ushort* ga = A + (size_t)(m0 + tr) * K + scb * 8;
  const ushort* gb = Bw + (size_t)(n0 + tr) * K + scb * 8;

  for (int k0 = 0; k0 < K; k0 += 32) {
    __builtin_amdgcn_global_load_lds((gas1_t)(ga + k0), (las3_t)(As + tid * 8), 16, 0, 0);
    __builtin_amdgcn_global_load_lds((gas1_t)(ga + (size_t)64 * K + k0), (las3_t)(As + 2048 + tid * 8), 16, 0, 0);
    __builtin_amdgcn_global_load_lds((gas1_t)(gb + k0), (las3_t)(Bs + tid * 8), 16, 0, 0);
    __builtin_amdgcn_global_load_lds((gas1_t)(gb + (size_t)64 * K + k0), (las3_t)(Bs + 2048 + tid * 8), 16, 0, 0);
    __syncthreads();
    s16x8 af[4], bf[4];
#pragma unroll
    for (int i = 0; i < 4; i++)
      af[i] = *(const s16x8*)(As + (wm + i * 16 + l16) * 32 + (quad ^ fsw) * 8);
#pragma unroll
    for (int n = 0; n < 4; n++)
      bf[n] = *(const s16x8*)(Bs + (wn + n * 16 + l16) * 32 + (quad ^ fsw) * 8);
#pragma unroll
    for (int i = 0; i < 4; i++)
#pragma unroll
      for (int n = 0; n < 4; n++)
        acc[i][n] = __builtin_amdgcn_mfma_f32_16x16x32_bf16(af[i], bf[n], acc[i][n], 0, 0, 0);
    __syncthreads();
  }

  const int sec = n0 / 768;  // 0=q, 1=k, 2=v
  if (sec < 2) {
    ushort* dst = sec == 0 ? Qb : Kb;
#pragma unroll
    for (int i = 0; i < 4; i++) {
      int row0 = m0 + wm + i * 16 + quad * 4;
#pragma unroll
      for (int nt = 0; nt < 4; nt++) {
        int col = n0 + wn + nt * 16 + l16;
        int nn = col - sec * 768;
        int h = nn >> 6, d = nn & 63;
        int ip = (d >> 1) & 31;
        float sgn = (d & 1) ? 1.f : -1.f;
#pragma unroll
        for (int r = 0; r < 4; r++) {
          int rrow = row0 + r;
          int t = rrow & (T_ - 1), bb = rrow >> 11;
          float v = acc[i][nt][r];
          float partner = __shfl_xor(v, 1);
          float2 cs = cs2[t * 32 + ip];
          float out = fmaf(v, cs.x, sgn * partner * cs.y);
          dst[((size_t)(bb * H_ + h) * T_ + t) * DH + d] = f2b(out);
        }
      }
    }
  } else {
#pragma unroll
    for (int i = 0; i < 4; i++) {
      int row0 = m0 + wm + i * 16 + quad * 4;
      int t0 = row0 & (T_ - 1), b = row0 >> 11;
#pragma unroll
      for (int nt = 0; nt < 4; nt++) {
        int col = n0 + wn + nt * 16 + l16;
        int nn = col - 1536;
        int h = nn >> 6, d = nn & 63;
        ushort4 pk;
        pk.x = f2b(acc[i][nt][0]); pk.y = f2b(acc[i][nt][1]);
        pk.z = f2b(acc[i][nt][2]); pk.w = f2b(acc[i][nt][3]);
        *(ushort4*)(Vt + ((size_t)(b * H_ + h) * DH + d) * T_ + t0) = pk;
      }
    }
  }
}

// ---------------- output GEMM (R8 form: 128x64, BK=32, swizzled) -------------
__global__ __launch_bounds__(256) void gemm_out(
    const ushort* __restrict__ A, const ushort* __restrict__ Bw, float* __restrict__ C) {
  const int K = 768, N = 768;
  __shared__ ushort As[128 * 32];
  __shared__ ushort Bs[64 * 32];
  const int m0 = blockIdx.y * 128, n0 = blockIdx.x * 64;
  const int tid = threadIdx.x;
  const int wave = tid >> 6, lane = tid & 63;
  const int wm = wave * 32;
  const int quad = lane >> 4, l16 = lane & 15;
  const int tr = tid >> 2;
  const int scb = (tid & 3) ^ ((tr >> 1) & 3);
  const int fsw = (l16 >> 1) & 3;

  f32x4 acc[2][4] = {};

  const ushort* ga = A + (size_t)(m0 + tr) * K + scb * 8;
  const ushort* gb = Bw + (size_t)(n0 + tr) * K + scb * 8;

  for (int k0 = 0; k0 < K; k0 += 32) {
    __builtin_amdgcn_global_load_lds((gas1_t)(ga + k0), (las3_t)(As + tid * 8), 16, 0, 0);
    __builtin_amdgcn_global_load_lds((gas1_t)(ga + (size_t)64 * K + k0), (las3_t)(As + 2048 + tid * 8), 16, 0, 0);
    __builtin_amdgcn_global_load_lds((gas1_t)(gb + k0), (las3_t)(Bs + tid * 8), 16, 0, 0);
    __syncthreads();
    s16x8 af[2], bf[4];
#pragma unroll
    for (int i = 0; i < 2; i++)
      af[i] = *(const s16x8*)(As + (wm + i * 16 + l16) * 32 + (quad ^ fsw) * 8);
#pragma unroll
    for (int n = 0; n < 4; n++)
      bf[n] = *(const s16x8*)(Bs + (n * 16 + l16) * 32 + (quad ^ fsw) * 8);
#pragma unroll
    for (int i = 0; i < 2; i++)
#pragma unroll
      for (int n = 0; n < 4; n++)
        acc[i][n] = __builtin_amdgcn_mfma_f32_16x16x32_bf16(af[i], bf[n], acc[i][n], 0, 0, 0);
    __syncthreads();
  }

#pragma unroll
  for (int i = 0; i < 2; i++) {
    int row = m0 + wm + i * 16 + quad * 4;
#pragma unroll
    for (int n = 0; n < 4; n++) {
      int col = n0 + n * 16 + l16;
#pragma unroll
      for (int r = 0; r < 4; r++)
        C[(size_t)(row + r) * N + col] = acc[i][n][r];
    }
  }
}

// ---------------- causal flash attention v7 ----------------------------------
// grid (48 bh, 16 j). Block handles q-slices j and 31-j: exactly 33 MFMA
// tile-units per block (perfect balance), one K/V stage shared by both.
// S^T = K·Q^T (operand swap, same register data) -> each lane's 4 P values are
// kv-consecutive: packed b64 P writes (stride 68 ushorts = conflict-free).
// Single-buffered 25 KB LDS, 4 blocks/CU.
#define EXP2SCALE 0.18033688f   /* 0.125 * log2(e) */
#define EXP2OFF  17.312340f     /* 12 * log2(e) */
__global__ __launch_bounds__(256, 4) void attn(const ushort* __restrict__ Qb, const ushort* __restrict__ Kb,
                                               const ushort* __restrict__ Vt, ushort* __restrict__ Ob) {
  const int bh = blockIdx.x;
  const int j = blockIdx.y;  // pair (j, 31-j)
  const int tid = threadIdx.x, wave = tid >> 6, lane = tid & 63;
  const int quad = lane >> 4, l16 = lane & 15;
  const int b = bh / H_, h = bh % H_;
  const ushort* Qp = Qb + (size_t)bh * T_ * DH;
  const ushort* Kp = Kb + (size_t)bh * T_ * DH;
  const ushort* Vp = Vt + (size_t)bh * DH * T_;

  __shared__ ushort Ks[64 * 64];
  __shared__ ushort Vs[64 * 64];
  __shared__ ushort P[4][16][68];  // [wave][q=l16][kv], stride 68

  const int qb0 = j * 64 + wave * 16;
  const int qb1 = (31 - j) * 64 + wave * 16;

  s16x8 aq[2][2];
  {
    const ushort* qp0 = Qp + (size_t)(qb0 + l16) * DH + quad * 8;
    aq[0][0] = *(const s16x8*)qp0;
    aq[0][1] = *(const s16x8*)(qp0 + 32);
    const ushort* qp1 = Qp + (size_t)(qb1 + l16) * DH + quad * 8;
    aq[1][0] = *(const s16x8*)qp1;
    aq[1][1] = *(const s16x8*)(qp1 + 32);
  }
  f32x4 o[2][4] = {};
  float rsum[2] = {0.f, 0.f};  // per-lane partial for q = qb_m + l16

  const int ntile = 32 - j;
  const int srow = tid >> 3;
  const int scbK = (tid & 7) ^ (srow & 7);
  const int swz = l16 & 7;

  for (int c = 0; c < ntile; c++) {
    const int kv0 = c * 64;
    __syncthreads();  // previous tile's LDS reads complete
    __builtin_amdgcn_global_load_lds((gas1_t)(Kp + (size_t)(kv0 + srow) * DH + scbK * 8),
                                     (las3_t)(Ks + tid * 8), 16, 0, 0);
    __builtin_amdgcn_global_load_lds((gas1_t)(Kp + (size_t)(kv0 + srow + 32) * DH + scbK * 8),
                                     (las3_t)(Ks + 2048 + tid * 8), 16, 0, 0);
    __builtin_amdgcn_global_load_lds((gas1_t)(Vp + (size_t)srow * T_ + kv0 + scbK * 8),
                                     (las3_t)(Vs + tid * 8), 16, 0, 0);
    __builtin_amdgcn_global_load_lds((gas1_t)(Vp + (size_t)(srow + 32) * T_ + kv0 + scbK * 8),
                                     (las3_t)(Vs + 2048 + tid * 8), 16, 0, 0);
    __syncthreads();  // staging visible

    s16x8 kf[4][2];
#pragma unroll
    for (int nt = 0; nt < 4; nt++) {
      const ushort* kr = Ks + (nt * 16 + l16) * 64;
      kf[nt][0] = *(const s16x8*)(kr + ((quad ^ swz) * 8));
      kf[nt][1] = *(const s16x8*)(kr + (((4 + quad) ^ swz) * 8));
    }
    s16x8 bv[4][2];
#pragma unroll
    for (int dt = 0; dt < 4; dt++) {
      const ushort* vr = Vs + (dt * 16 + l16) * 64;
      bv[dt][0] = *(const s16x8*)(vr + ((quad ^ swz) * 8));
      bv[dt][1] = *(const s16x8*)(vr + (((4 + quad) ^ swz) * 8));
    }

#pragma unroll
    for (int m = 0; m < 2; m++) {
      const int qbm = m ? qb1 : qb0;
      if (kv0 > qbm + 15) continue;  // slice done (uniform within wave)
      // S^T[kv][q]: A = K frag, B = Q frag (same data, swapped roles)
      f32x4 st[4] = {};
#pragma unroll
      for (int nt = 0; nt < 4; nt++) {
        st[nt] = __builtin_amdgcn_mfma_f32_16x16x32_bf16(kf[nt][0], aq[m][0], st[nt], 0, 0, 0);
        st[nt] = __builtin_amdgcn_mfma_f32_16x16x32_bf16(kf[nt][1], aq[m][1], st[nt], 0, 0, 0);
      }
      // lane holds kv = kv0 + nt*16 + quad*4 + r, q = qbm + l16
      if (kv0 + 63 <= qbm) {  // fully unmasked
#pragma unroll
        for (int nt = 0; nt < 4; nt++) {
          float p[4];
#pragma unroll
          for (int r = 0; r < 4; r++) {
            p[r] = __builtin_amdgcn_exp2f(fmaf(st[nt][r], EXP2SCALE, -EXP2OFF));
            rsum[m] += p[r];
          }
          uint2 pk;
          pk.x = __builtin_amdgcn_perm(fbits(p[1]) + 0x8000u, fbits(p[0]) + 0x8000u, 0x07060302u);
          pk.y = __builtin_amdgcn_perm(fbits(p[3]) + 0x8000u, fbits(p[2]) + 0x8000u, 0x07060302u);
          *(uint2*)&P[wave][l16][nt * 16 + quad * 4] = pk;
        }
      } else {  // diagonal tile
        const int q = qbm + l16;
#pragma unroll
        for (int nt = 0; nt < 4; nt++) {
          float p[4];
#pragma unroll
          for (int r = 0; r < 4; r++) {
            int kv = kv0 + nt * 16 + quad * 4 + r;
            p[r] = (kv <= q) ? __builtin_amdgcn_exp2f(fmaf(st[nt][r], EXP2SCALE, -EXP2OFF)) : 0.f;
            rsum[m] += p[r];
          }
          uint2 pk;
          pk.x = __builtin_amdgcn_perm(fbits(p[1]) + 0x8000u, fbits(p[0]) + 0x8000u, 0x07060302u);
          pk.y = __builtin_amdgcn_perm(fbits(p[3]) + 0x8000u, fbits(p[2]) + 0x8000u, 0x07060302u);
          *(uint2*)&P[wave][l16][nt * 16 + quad * 4] = pk;
        }
      }
      // P A-fragment: lane needs P[q=l16][kv = half*32 + quad*8 + jj]
      s16x8 ap0 = *(const s16x8*)&P[wave][l16][quad * 8];
      s16x8 ap1 = *(const s16x8*)&P[wave][l16][32 + quad * 8];
#pragma unroll
      for (int dt = 0; dt < 4; dt++) {
        o[m][dt] = __builtin_amdgcn_mfma_f32_16x16x32_bf16(ap0, bv[dt][0], o[m][dt], 0, 0, 0);
        o[m][dt] = __builtin_amdgcn_mfma_f32_16x16x32_bf16(ap1, bv[dt][1], o[m][dt], 0, 0, 0);
      }
    }
  }
  // rsum: sum over quads (lanes l16, l16+16, l16+32, l16+48)
#pragma unroll
  for (int m = 0; m < 2; m++) {
    rsum[m] += __shfl_xor(rsum[m], 16);
    rsum[m] += __shfl_xor(rsum[m], 32);
  }
  // redistribute: epilogue lane (quad,r) needs 1/rsum of q-row quad*4+r
  float rinv[2][4];
#pragma unroll
  for (int m = 0; m < 2; m++)
#pragma unroll
    for (int r = 0; r < 4; r++)
      rinv[m][r] = __builtin_amdgcn_rcpf(__shfl(rsum[m], quad * 4 + r));
#pragma unroll
  for (int m = 0; m < 2; m++) {
    const int qrow = (m ? (31 - j) : j) * 64 + wave * 16 + quad * 4;
#pragma unroll
    for (int dt = 0; dt < 4; dt++)
#pragma unroll
      for (int r = 0; r < 4; r++) {
        int q = qrow + r;
        Ob[(size_t)(b * T_ + q) * DM + h * 64 + dt * 16 + l16] = f2b(o[m][dt][r] * rinv[m][r]);
      }
  }
}

extern "C" void kernel_launch(void* const* d_in, const int* in_sizes, int n_in,
                              void* d_out, int out_size, void* d_ws, size_t ws_size,
                              hipStream_t stream) {
  const float* x = (const float*)d_in[0];
  const float* rc = (const float*)d_in[1];
  const float* rs = (const float*)d_in[2];
  const float* wq = (const float*)d_in[3];
  const float* wk = (const float*)d_in[4];
  const float* wv = (const float*)d_in[5];
  const float* wo = (const float*)d_in[6];

  char* ws = (char*)d_ws;
  ushort* xb   = (ushort*)(ws);                 // 12,582,912
  ushort* wqkv = (ushort*)(ws + 12582912);      //  3,538,944
  ushort* wob  = (ushort*)(ws + 16121856);      //  1,179,648
  float2* cs2  = (float2*)(ws + 17301504);      //    524,288
  ushort* Qb   = (ushort*)(ws + 17825792);      // 12,582,912
  ushort* Kb   = (ushort*)(ws + 30408704);      // 12,582,912
  ushort* Vt   = (ushort*)(ws + 42991616);      // 12,582,912
  ushort* Ob   = (ushort*)(ws + 55574528);      // 12,582,912

  prep<<<8512, 256, 0, stream>>>(x, wq, wk, wv, wo, rc, rs, xb, wqkv, wob, cs2);

  gemm_qkv<<<dim3(18, 64), 256, 0, stream>>>(xb, wqkv, cs2, Qb, Kb, Vt);

  attn<<<dim3(48, 16), 256, 0, stream>>>(Qb, Kb, Vt, Ob);

  gemm_out<<<dim3(12, 64), 256, 0, stream>>>(Ob, wob, (float*)d_out);
}